// Round 3
// baseline (54.855 us; speedup 1.0000x reference)
//
#include <hip/hip_runtime.h>
#include <hip/hip_bf16.h>

// Tsit5 (Tsitouras 2011) coefficients
#define A21 0.161f
#define A31 (-0.008480655492356989f)
#define A32 0.335480655492357f
#define A41 2.8971530571054935f
#define A42 (-6.359448489975075f)
#define A43 4.3622954328695815f
#define A51 5.325864828439257f
#define A52 (-11.748883564062828f)
#define A53 7.4955393428898365f
#define A54 (-0.09249506636175525f)
#define A61 5.86145544294642f
#define A62 (-12.92096931784711f)
#define A63 8.159367898576159f
#define A64 (-0.071584973281401f)
#define A65 (-0.028269050394068383f)
#define B1 0.09646076681806523f
#define B2 0.01f
#define B3 0.4798896504144996f
#define B4 1.379008574103742f
#define B5 (-3.290069515436081f)
#define B6 2.324710524099774f

#define NORM 32768.0f
#define SUBSTEPS 8
#define IN_DIM 4096
#define OUT_DIM 1024

typedef float f32x4 __attribute__((ext_vector_type(4)));

// Each thread computes 4 adjacent output pixels -> 16B/lane stores.
__global__ __launch_bounds__(256) void ODERamp_kernel(
    const float* __restrict__ in,      // [4096, 4096]
    const int* __restrict__ ng_ptr,    // scalar ngroups
    float* __restrict__ out)           // [ngroups, 1024, 1024]
{
    const int t = blockIdx.x * blockDim.x + threadIdx.x;   // 0 .. 256K-1
    const int p = t << 2;             // base output pixel (4 per thread)
    const int r = p >> 10;            // output row
    const int c = p & 1023;           // base output col (multiple of 4)

    // 4x4 block sums for 4 adjacent output pixels: input rows 4r..4r+3,
    // cols 4c..4c+15. 16 nontemporal 16B loads, full cacheline use.
    float s0 = 0.0f, s1 = 0.0f, s2 = 0.0f, s3 = 0.0f;
#pragma unroll
    for (int i = 0; i < 4; ++i) {
        const f32x4* row = reinterpret_cast<const f32x4*>(
            in + (size_t)(4 * r + i) * IN_DIM + 4 * c);
        const f32x4 v0 = __builtin_nontemporal_load(row + 0);
        const f32x4 v1 = __builtin_nontemporal_load(row + 1);
        const f32x4 v2 = __builtin_nontemporal_load(row + 2);
        const f32x4 v3 = __builtin_nontemporal_load(row + 3);
        s0 += (v0.x + v0.y) + (v0.z + v0.w);
        s1 += (v1.x + v1.y) + (v1.z + v1.w);
        s2 += (v2.x + v2.y) + (v2.z + v2.w);
        s3 += (v3.x + v3.y) + (v3.z + v3.w);
    }

    const int ngroups = *ng_ptr;                 // uniform scalar load
    const float dt = 1.0f / (float)(ngroups * SUBSTEPS);

    // Tsit5 stability polynomial R(z) for y' = I*(1-y); per-substep factor
    // f = 1 - R(z), per-group factor f^8.
    float f8v[4];
    const float sv[4] = {s0, s1, s2, s3};
#pragma unroll
    for (int j = 0; j < 4; ++j) {
        const float z  = sv[j] * (1.0f / NORM) * dt;
        const float q2 = 1.0f - A21 * z;
        const float q3 = 1.0f - z * (A31 + A32 * q2);
        const float q4 = 1.0f - z * (A41 + A42 * q2 + A43 * q3);
        const float q5 = 1.0f - z * (A51 + A52 * q2 + A53 * q3 + A54 * q4);
        const float q6 = 1.0f - z * (A61 + A62 * q2 + A63 * q3 + A64 * q4 + A65 * q5);
        const float R  = z * (B1 + B2 * q2 + B3 * q3 + B4 * q4 + B5 * q5 + B6 * q6);
        const float f  = 1.0f - R;
        const float f2 = f * f;
        const float f4 = f2 * f2;
        f8v[j] = f4 * f4;
    }

    float a0 = 1.0f, a1 = 1.0f, a2 = 1.0f, a3 = 1.0f;  // (1 - y) products
    f32x4* outp = reinterpret_cast<f32x4*>(out + p);
    const size_t plane4 = (size_t)(OUT_DIM * OUT_DIM) / 4;   // f32x4 stride
    for (int g = 0; g < ngroups; ++g) {
        a0 *= f8v[0]; a1 *= f8v[1]; a2 *= f8v[2]; a3 *= f8v[3];
        f32x4 o;
        o.x = NORM - NORM * a0;
        o.y = NORM - NORM * a1;
        o.z = NORM - NORM * a2;
        o.w = NORM - NORM * a3;
        __builtin_nontemporal_store(o, outp);
        outp += plane4;
    }
}

extern "C" void kernel_launch(void* const* d_in, const int* in_sizes, int n_in,
                              void* d_out, int out_size, void* d_ws, size_t ws_size,
                              hipStream_t stream) {
    const float* illum = (const float*)d_in[0];
    const int* ng = (const int*)d_in[1];
    float* out = (float*)d_out;

    const int n_thr = (OUT_DIM * OUT_DIM) / 4;   // 262,144 threads
    const int block = 256;
    const int grid = n_thr / block;              // 1024 blocks

    ODERamp_kernel<<<grid, block, 0, stream>>>(illum, ng, out);
}

// Round 4
// 38.508 us; speedup vs baseline: 1.4245x; 1.4245x over previous
//
#include <hip/hip_runtime.h>
#include <hip/hip_bf16.h>

// Tsit5 (Tsitouras 2011) coefficients
#define A21 0.161f
#define A31 (-0.008480655492356989f)
#define A32 0.335480655492357f
#define A41 2.8971530571054935f
#define A42 (-6.359448489975075f)
#define A43 4.3622954328695815f
#define A51 5.325864828439257f
#define A52 (-11.748883564062828f)
#define A53 7.4955393428898365f
#define A54 (-0.09249506636175525f)
#define A61 5.86145544294642f
#define A62 (-12.92096931784711f)
#define A63 8.159367898576159f
#define A64 (-0.071584973281401f)
#define A65 (-0.028269050394068383f)
#define B1 0.09646076681806523f
#define B2 0.01f
#define B3 0.4798896504144996f
#define B4 1.379008574103742f
#define B5 (-3.290069515436081f)
#define B6 2.324710524099774f

#define NORM 32768.0f
#define SUBSTEPS 8
#define IN_DIM 4096
#define OUT_DIM 1024

typedef float f32x4 __attribute__((ext_vector_type(4)));

// Each thread computes 4 adjacent output pixels -> 16B/lane loads+stores.
// NO non-temporal hints: the 192MB working set fits the 256MB Infinity
// Cache; normal caching lets L3 absorb the streams (nt cost +59% in R2/R3).
__global__ __launch_bounds__(256) void ODERamp_kernel(
    const float* __restrict__ in,      // [4096, 4096]
    const int* __restrict__ ng_ptr,    // scalar ngroups
    float* __restrict__ out)           // [ngroups, 1024, 1024]
{
    const int t = blockIdx.x * blockDim.x + threadIdx.x;   // 0 .. 256K-1
    const int p = t << 2;             // base output pixel (4 per thread)
    const int r = p >> 10;            // output row
    const int c = p & 1023;           // base output col (multiple of 4)

    // 4x4 block sums for 4 adjacent output pixels: input rows 4r..4r+3,
    // cols 4c..4c+15. 16 coalesced 16B loads, full cacheline use.
    float s0 = 0.0f, s1 = 0.0f, s2 = 0.0f, s3 = 0.0f;
#pragma unroll
    for (int i = 0; i < 4; ++i) {
        const f32x4* row = reinterpret_cast<const f32x4*>(
            in + (size_t)(4 * r + i) * IN_DIM + 4 * c);
        const f32x4 v0 = row[0];
        const f32x4 v1 = row[1];
        const f32x4 v2 = row[2];
        const f32x4 v3 = row[3];
        s0 += (v0.x + v0.y) + (v0.z + v0.w);
        s1 += (v1.x + v1.y) + (v1.z + v1.w);
        s2 += (v2.x + v2.y) + (v2.z + v2.w);
        s3 += (v3.x + v3.y) + (v3.z + v3.w);
    }

    const int ngroups = *ng_ptr;                 // uniform scalar load
    const float dt = 1.0f / (float)(ngroups * SUBSTEPS);

    // Tsit5 stability polynomial R(z) for y' = I*(1-y); per-substep factor
    // f = 1 - R(z), per-group factor f^8.
    float f8v[4];
    const float sv[4] = {s0, s1, s2, s3};
#pragma unroll
    for (int j = 0; j < 4; ++j) {
        const float z  = sv[j] * (1.0f / NORM) * dt;
        const float q2 = 1.0f - A21 * z;
        const float q3 = 1.0f - z * (A31 + A32 * q2);
        const float q4 = 1.0f - z * (A41 + A42 * q2 + A43 * q3);
        const float q5 = 1.0f - z * (A51 + A52 * q2 + A53 * q3 + A54 * q4);
        const float q6 = 1.0f - z * (A61 + A62 * q2 + A63 * q3 + A64 * q4 + A65 * q5);
        const float R  = z * (B1 + B2 * q2 + B3 * q3 + B4 * q4 + B5 * q5 + B6 * q6);
        const float f  = 1.0f - R;
        const float f2 = f * f;
        const float f4 = f2 * f2;
        f8v[j] = f4 * f4;
    }

    float a0 = 1.0f, a1 = 1.0f, a2 = 1.0f, a3 = 1.0f;  // (1 - y) products
    f32x4* outp = reinterpret_cast<f32x4*>(out + p);
    const size_t plane4 = (size_t)(OUT_DIM * OUT_DIM) / 4;   // f32x4 stride
    for (int g = 0; g < ngroups; ++g) {
        a0 *= f8v[0]; a1 *= f8v[1]; a2 *= f8v[2]; a3 *= f8v[3];
        f32x4 o;
        o.x = NORM - NORM * a0;
        o.y = NORM - NORM * a1;
        o.z = NORM - NORM * a2;
        o.w = NORM - NORM * a3;
        *outp = o;
        outp += plane4;
    }
}

extern "C" void kernel_launch(void* const* d_in, const int* in_sizes, int n_in,
                              void* d_out, int out_size, void* d_ws, size_t ws_size,
                              hipStream_t stream) {
    const float* illum = (const float*)d_in[0];
    const int* ng = (const int*)d_in[1];
    float* out = (float*)d_out;

    const int n_thr = (OUT_DIM * OUT_DIM) / 4;   // 262,144 threads
    const int block = 256;
    const int grid = n_thr / block;              // 1024 blocks

    ODERamp_kernel<<<grid, block, 0, stream>>>(illum, ng, out);
}